// Round 4
// baseline (351.832 us; speedup 1.0000x reference)
//
#include <hip/hip_runtime.h>

#define BATCH 16384
#define DIM 128
#define NLINK 500
#define NG 16           // 16 groups x 32 lanes = 512 threads
#define CAP 128         // per-link bucket capacity (Poisson mean 32.8)

// async global->LDS, 16B per lane; LDS dst is wave-uniform base + lane*16.
__device__ __forceinline__ void gload_lds16(const float* g, float* l) {
    __builtin_amdgcn_global_load_lds(
        (const __attribute__((address_space(1))) void*)g,
        (__attribute__((address_space(3))) void*)l, 16, 0, 0);
}

#define SBAR()    __builtin_amdgcn_s_barrier()
#define SCHEDB()  __builtin_amdgcn_sched_barrier(0)
#define VMWAIT(n) asm volatile("s_waitcnt vmcnt(" #n ")" ::: "memory")

__global__ void k_init(float* __restrict__ out) {
    if (threadIdx.x == 0) out[0] = 0.0f;
}

#define FMA4(acc, m, s)                                          \
    acc.x = fmaf(m.x, s, acc.x); acc.y = fmaf(m.y, s, acc.y);    \
    acc.z = fmaf(m.z, s, acc.z); acc.w = fmaf(m.w, s, acc.w);

// pair-scheme d4 body: 4 M-reads feed 4 accumulators (pos/neg x 2 samples)
template <int LO, int HI>
__device__ __forceinline__ void sweep(const float4* M4, int q,
    const float4* Vp0, const float4* Vn0, const float4* Vp1, const float4* Vn1,
    float4& ap0, float4& an0, float4& ap1, float4& an1)
{
    #pragma unroll
    for (int d4 = LO; d4 < HI; d4++) {
        float4 vp0 = Vp0[d4], vn0 = Vn0[d4];     // group broadcasts
        float4 vp1 = Vp1[d4], vn1 = Vn1[d4];
        float4 m0 = M4[(4 * d4 + 0) * 32 + q];
        float4 m1 = M4[(4 * d4 + 1) * 32 + q];
        float4 m2 = M4[(4 * d4 + 2) * 32 + q];
        float4 m3 = M4[(4 * d4 + 3) * 32 + q];
        FMA4(ap0, m0, vp0.x) FMA4(an0, m0, vn0.x)
        FMA4(ap1, m0, vp1.x) FMA4(an1, m0, vn1.x)
        FMA4(ap0, m1, vp0.y) FMA4(an0, m1, vn0.y)
        FMA4(ap1, m1, vp1.y) FMA4(an1, m1, vn1.y)
        FMA4(ap0, m2, vp0.z) FMA4(an0, m2, vn0.z)
        FMA4(ap1, m2, vp1.z) FMA4(an1, m2, vn1.z)
        FMA4(ap0, m3, vp0.w) FMA4(an0, m3, vn0.w)
        FMA4(ap1, m3, vp1.w) FMA4(an1, m3, vn1.w)
    }
}

#define ROW(idx) (((const float4*)(node_w + (size_t)(idx) * DIM))[q])
#define DIFFW(dst, X, Y) {                                       \
    float4 w_;                                                   \
    w_.x = X.x - Y.x; w_.y = X.y - Y.y;                          \
    w_.z = X.z - Y.z; w_.w = X.w - Y.w;                          \
    ((float4*)(dst))[q] = w_; }
#define LOSS(ACp, ACn)                                           \
    (fabsf(ACp.x + re.x) + fabsf(ACp.y + re.y) +                 \
     fabsf(ACp.z + re.z) + fabsf(ACp.w + re.w)                   \
   - fabsf(ACn.x + re.x) - fabsf(ACn.y + re.y)                   \
   - fabsf(ACn.z + re.z) - fabsf(ACn.w + re.w))

// One block per link; 16 groups x 32 lanes. VMEM issue order is load-bearing:
// [r][idx1][rows1][idx2][re][M x8 in d-order] so M = youngest 8 ops. Counted
// vmcnt(6/4/2) then releases 16-KB M-quarters for pair-1 chunk sweeps (stage
// overlaps compute); pair-2 rows issued after chunk 2 make vmcnt(8) = M done.
// All loads unconditional (clamped idx) -> uniform per-wave vmcnt streams.
// Rounds 2+ are barrier-free with register prefetch (proven R2 structure).
__global__ __launch_bounds__(512, 2) void k_fused(
    const float* __restrict__ node_w, const float* __restrict__ link_w,
    const float* __restrict__ transfer_w,
    const int* __restrict__ sp, const int* __restrict__ tp,
    const int* __restrict__ sn, const int* __restrict__ tn,
    const int* __restrict__ r, float* __restrict__ out)
{
    __shared__ float Ms[DIM * DIM];          // 64 KB, M row-major [d][e]
    __shared__ float dv[NG * 4 * DIM];       // 32 KB: per group p0,n0,p1,n1
    __shared__ int   slist[CAP];
    __shared__ int   cnt;
    __shared__ float lossbuf[NG];

    const int link = blockIdx.x;
    const int t = threadIdx.x;
    const int g = t >> 5;
    const int q = t & 31;

    if (t == 0) cnt = 0;
    __syncthreads();

    // ---- scan r -> slist (must finish before gathers can be addressed) ----
    int4 rv[8];
    #pragma unroll
    for (int j = 0; j < 8; j++) rv[j] = ((const int4*)r)[j * 512 + t];
    #pragma unroll
    for (int j = 0; j < 8; j++) {
        const int bi = (j * 512 + t) * 4;
        if (rv[j].x == link) slist[atomicAdd(&cnt, 1)] = bi;
        if (rv[j].y == link) slist[atomicAdd(&cnt, 1)] = bi + 1;
        if (rv[j].z == link) slist[atomicAdd(&cnt, 1)] = bi + 2;
        if (rv[j].w == link) slist[atomicAdd(&cnt, 1)] = bi + 3;
    }
    __syncthreads();                 // nothing in VMEM flight: cheap drain
    const int count = cnt;

    // ---- pair-1 / pair-2 indices (clamped; unconditional loads) ----
    const bool act0 = (g < count);
    const bool act1 = (g + 16 < count);
    int b0 = 0, b1 = 0, nb0 = 0, nb1 = 0;
    if (count > 0) {
        b0  = slist[act0 ? g : 0];
        b1  = act1 ? slist[g + 16] : b0;
        const int nk = g + 32;
        nb0 = (nk < count) ? slist[nk] : b0;
        nb1 = (nk + 16 < count) ? slist[nk + 16] : nb0;
    }
    // idx1
    int isp0 = sp[b0], itp0 = tp[b0], isn0 = sn[b0], itn0 = tn[b0];
    int isp1 = sp[b1], itp1 = tp[b1], isn1 = sn[b1], itn1 = tn[b1];
    SCHEDB();
    // rows1
    float4 A0 = ROW(isp0), C0 = ROW(itp0), E0 = ROW(isn0), F0 = ROW(itn0);
    float4 A1 = ROW(isp1), C1 = ROW(itp1), E1 = ROW(isn1), F1 = ROW(itn1);
    SCHEDB();
    // idx2 + link embedding (older than M: harmless to chunk waits)
    int jsp0 = sp[nb0], jtp0 = tp[nb0], jsn0 = sn[nb0], jtn0 = tn[nb0];
    int jsp1 = sp[nb1], jtp1 = tp[nb1], jsn1 = sn[nb1], jtn1 = tn[nb1];
    const float4 re = ((const float4*)(link_w + (size_t)link * DIM))[q];
    SCHEDB();
    // M stage: 8 pieces in ascending d-order (piece i = rows 16i..16i+15)
    {
        const float* src = transfer_w + (size_t)link * (DIM * DIM);
        #pragma unroll
        for (int i = 0; i < 8; i++) {
            const int c = (t + 512 * i) * 4;
            gload_lds16(src + c, Ms + c);
            SCHEDB();                 // pin piece order (chunk identity)
        }
    }

    float* p0r = dv + (g * 4 + 0) * DIM;
    float* n0r = dv + (g * 4 + 1) * DIM;
    float* p1r = dv + (g * 4 + 2) * DIM;
    float* n1r = dv + (g * 4 + 3) * DIM;
    // diffs for pair 1 (compiler waits rows1 only: M is younger)
    DIFFW(p0r, A0, C0) DIFFW(n0r, E0, F0)
    DIFFW(p1r, A1, C1) DIFFW(n1r, E1, F1)

    const float4* M4  = (const float4*)Ms;
    const float4* Vp0 = (const float4*)p0r;
    const float4* Vn0 = (const float4*)n0r;
    const float4* Vp1 = (const float4*)p1r;
    const float4* Vn1 = (const float4*)n1r;
    float4 ap0 = {0,0,0,0}, an0 = {0,0,0,0}, ap1 = {0,0,0,0}, an1 = {0,0,0,0};

    // ---- chunked pair-1 sweep, overlapped with M arrival ----
    VMWAIT(6); SCHEDB(); SBAR();              // M quarter 0 (d4 0..7) in LDS
    sweep<0, 8>(M4, q, Vp0, Vn0, Vp1, Vn1, ap0, an0, ap1, an1);
    VMWAIT(4); SCHEDB(); SBAR();              // quarter 1
    sweep<8, 16>(M4, q, Vp0, Vn0, Vp1, Vn1, ap0, an0, ap1, an1);
    VMWAIT(2); SCHEDB(); SBAR();              // quarter 2
    sweep<16, 24>(M4, q, Vp0, Vn0, Vp1, Vn1, ap0, an0, ap1, an1);
    // rows2 prefetch (unconditional; becomes the youngest 8 ops)
    float4 pa0 = ROW(jsp0), pc0 = ROW(jtp0), pe0 = ROW(jsn0), pf0 = ROW(jtn0);
    float4 pa1 = ROW(jsp1), pc1 = ROW(jtp1), pe1 = ROW(jsn1), pf1 = ROW(jtn1);
    SCHEDB();
    VMWAIT(8); SCHEDB(); SBAR();              // quarter 3 (rows2 still flying)
    sweep<24, 32>(M4, q, Vp0, Vn0, Vp1, Vn1, ap0, an0, ap1, an1);

    float lsum = 0.0f;
    {
        float v0 = LOSS(ap0, an0);
        float v1 = LOSS(ap1, an1);
        #pragma unroll
        for (int o = 16; o >= 1; o >>= 1) {
            v0 += __shfl_xor(v0, o, 32);
            v1 += __shfl_xor(v1, o, 32);
        }
        if (q == 0) {
            if (act0) lsum += fmaxf(v0 + 1.0f, 0.0f);
            if (act1) lsum += fmaxf(v1 + 1.0f, 0.0f);
        }
    }

    // ---- rounds 2+: barrier-free, register-prefetched (R2 structure) ----
    int myk = g + 32;
    while (myk < count) {
        const bool a1 = (myk + 16) < count;
        // stage current pair's diffs from prefetched rows (compiler waits them)
        DIFFW(p0r, pa0, pc0) DIFFW(n0r, pe0, pf0)
        DIFFW(p1r, pa1, pc1) DIFFW(n1r, pe1, pf1)
        // prefetch next pair
        const int nx = myk + 32;
        const bool h2 = nx < count;
        {
            const int mb0 = h2 ? slist[nx] : 0;
            const int mb1 = (h2 && nx + 16 < count) ? slist[nx + 16] : mb0;
            if (h2) {
                const int ksp0 = sp[mb0], ktp0 = tp[mb0], ksn0 = sn[mb0], ktn0 = tn[mb0];
                const int ksp1 = sp[mb1], ktp1 = tp[mb1], ksn1 = sn[mb1], ktn1 = tn[mb1];
                pa0 = ROW(ksp0); pc0 = ROW(ktp0); pe0 = ROW(ksn0); pf0 = ROW(ktn0);
                pa1 = ROW(ksp1); pc1 = ROW(ktp1); pe1 = ROW(ksn1); pf1 = ROW(ktn1);
            }
        }
        ap0 = {0,0,0,0}; an0 = {0,0,0,0}; ap1 = {0,0,0,0}; an1 = {0,0,0,0};
        sweep<0, 32>(M4, q, Vp0, Vn0, Vp1, Vn1, ap0, an0, ap1, an1);

        float v0 = LOSS(ap0, an0);
        float v1 = LOSS(ap1, an1);
        #pragma unroll
        for (int o = 16; o >= 1; o >>= 1) {
            v0 += __shfl_xor(v0, o, 32);
            v1 += __shfl_xor(v1, o, 32);
        }
        if (q == 0) {
            lsum += fmaxf(v0 + 1.0f, 0.0f);
            if (a1) lsum += fmaxf(v1 + 1.0f, 0.0f);
        }
        myk = nx;
    }

    if (q == 0) lossbuf[g] = lsum;
    __syncthreads();
    if (t == 0) {
        float s = 0.0f;
        #pragma unroll
        for (int i = 0; i < NG; i++) s += lossbuf[i];
        atomicAdd(out, s * (1.0f / BATCH));
    }
}

extern "C" void kernel_launch(void* const* d_in, const int* in_sizes, int n_in,
                              void* d_out, int out_size, void* d_ws, size_t ws_size,
                              hipStream_t stream) {
    const float* node_w     = (const float*)d_in[0];
    const float* link_w     = (const float*)d_in[1];
    const float* transfer_w = (const float*)d_in[2];
    const int* sp = (const int*)d_in[3];
    const int* tp = (const int*)d_in[4];
    const int* sn = (const int*)d_in[5];
    const int* tn = (const int*)d_in[6];
    const int* r  = (const int*)d_in[7];
    float* out = (float*)d_out;
    (void)d_ws; (void)ws_size;

    k_init<<<1, 64, 0, stream>>>(out);
    k_fused<<<NLINK, 512, 0, stream>>>(node_w, link_w, transfer_w,
                                       sp, tp, sn, tn, r, out);
}